// Round 4
// baseline (968.670 us; speedup 1.0000x reference)
//
#include <hip/hip_runtime.h>
#include <hip/hip_bf16.h>
#include <cstdint>

#define AS_GLOBAL __attribute__((address_space(1)))
#define AS_LDS    __attribute__((address_space(3)))

typedef __attribute__((ext_vector_type(8))) short bf16x8;
typedef __attribute__((ext_vector_type(4))) float f32x4;

static __device__ __forceinline__ ushort f2bf(float x) {
    union { float f; uint32_t u; } c;
    c.f = x;
    uint32_t u = c.u;
    u += 0x7fffu + ((u >> 16) & 1u);   // RTNE
    return (ushort)(u >> 16);
}
static __device__ __forceinline__ float bf2f(ushort u) {
    union { uint32_t i; float f; } c;
    c.i = ((uint32_t)u) << 16;
    return c.f;
}

// async global->LDS, 16B/lane. LDS dest = wave-uniform base + lane*16 (we pass base+lane*16).
static __device__ __forceinline__ void gload_lds16(const void* g, void* l) {
    __builtin_amdgcn_global_load_lds(
        (const AS_GLOBAL uint32_t*)(uintptr_t)g,
        (AS_LDS uint32_t*)(uint32_t)(uintptr_t)l,
        16, 0, 0);
}

// ---------------- [K,N] fp32 -> [N,K] bf16 transpose ----------------
__global__ __launch_bounds__(256)
void transpose_to_bf16(const float* __restrict__ w, ushort* __restrict__ wt, int K, int N) {
    __shared__ float tile[32][33];
    int bn = blockIdx.x * 32;
    int bk = blockIdx.y * 32;
    int tx = threadIdx.x & 31, ty = threadIdx.x >> 5;
    #pragma unroll
    for (int i = 0; i < 32; i += 8)
        tile[ty + i][tx] = w[(size_t)(bk + ty + i) * N + bn + tx];
    __syncthreads();
    #pragma unroll
    for (int i = 0; i < 32; i += 8)
        wt[(size_t)(bn + ty + i) * K + bk + tx] = f2bf(tile[tx][ty + i]);
}

// =====================================================================
// 256x256 8-phase GEMM, register-resident fragment pipeline.
// C[M,1024] = A[M,1024] * Bt[1024,1024](bf16). M=32768. BK=64, 16 K-tiles.
// EPI: 0=none 1=sigmoid 2=exp.  A_F32: fused fp32->bf16 A staging.  OUT_BF: bf16 C.
// =====================================================================
template<int EPI, int A_F32, int OUT_BF>
__global__ __launch_bounds__(512, 2)
void gemm256(const void* __restrict__ Av, const ushort* __restrict__ Bt,
             void* __restrict__ Cv) {
    constexpr int K = 1024, N = 1024;
    __shared__ ushort sA[2][16384];   // [buf][row*64 + physslot*8], 32KB each
    __shared__ ushort sB[2][16384];
    const int tid  = threadIdx.x;
    const int wid  = tid >> 6;
    const int lane = tid & 63;
    const int wr = wid >> 2, wc = wid & 3;        // 2 x 4 waves, each owns 128x64 of C
    const int lr = lane & 15, kb = lane >> 4;

    // XCD swizzle: 512 wgs = 8 xcds x 64; same-xcd blocks share a bm range (A reuse in L2)
    const int wg = blockIdx.x;
    const int xcd = wg & 7, local = wg >> 3;
    const int bm = xcd * 16 + (local >> 2);
    const int bn = local & 3;
    const int m0 = bm * 256, n0 = bn * 256;

    const float*  Af = (const float*)Av;
    const ushort* Ab = (const ushort*)Av;

    f32x4 acc[8][4] = {};
    bf16x8 afX[4][2], afY[4][2];      // ping-pong A fragment sets (one MQ half each)
    bf16x8 bvX[2][2], bvY[2][2];      // ping-pong B fragment sets (one NQ half each)
    float4 fa0, fa1, fa2, fa3;        // in-flight fp32 A (reg stage)
    const int arl  = tid >> 2;
    const int aseg = tid & 3;
    const int agr0 = ((arl >> 6) << 7) + (arl & 63);

    // ---- staging helpers (LDS linear dest, pre-swizzled global source) ----
    auto stageB = [&](int tile, int h) {
        ushort* buf = sB[tile & 1];
        const int kt0 = tile * 64;
        #pragma unroll
        for (int j = 0; j < 2; j++) {
            const int row0 = j * 128 + h * 32 + (wid >> 2) * 64 + (wid & 3) * 8;
            const int row  = row0 + (lane >> 3);
            const int kslot = (lane & 7) ^ (lane >> 3);
            gload_lds16(Bt + (size_t)(n0 + row) * K + kt0 + kslot * 8,
                        &buf[row * 64 + (lane & 7) * 8]);
        }
    };
    auto stageAbf = [&](int tile, int h) {
        ushort* buf = sA[tile & 1];
        const int kt0 = tile * 64;
        #pragma unroll
        for (int j = 0; j < 2; j++) {
            const int row0 = j * 128 + h * 64 + wid * 8;
            const int row  = row0 + (lane >> 3);
            const int kslot = (lane & 7) ^ (lane >> 3);
            gload_lds16(Ab + (size_t)(m0 + row) * K + kt0 + kslot * 8,
                        &buf[row * 64 + (lane & 7) * 8]);
        }
    };
    auto issueA = [&](int tile, int h) {
        const int row = agr0 + h * 64;
        const float* s = Af + (size_t)(m0 + row) * K + tile * 64 + aseg * 16;
        fa0 = *(const float4*)(s);     fa1 = *(const float4*)(s + 4);
        fa2 = *(const float4*)(s + 8); fa3 = *(const float4*)(s + 12);
    };
    auto writeAcore = [&](int tile, int h) {
        const int row = agr0 + h * 64;
        const int ks0 = (aseg * 2) ^ (row & 7);
        ushort* buf = sA[tile & 1];
        bf16x8 lo, hi;
        lo[0]=(short)f2bf(fa0.x); lo[1]=(short)f2bf(fa0.y); lo[2]=(short)f2bf(fa0.z); lo[3]=(short)f2bf(fa0.w);
        lo[4]=(short)f2bf(fa1.x); lo[5]=(short)f2bf(fa1.y); lo[6]=(short)f2bf(fa1.z); lo[7]=(short)f2bf(fa1.w);
        hi[0]=(short)f2bf(fa2.x); hi[1]=(short)f2bf(fa2.y); hi[2]=(short)f2bf(fa2.z); hi[3]=(short)f2bf(fa2.w);
        hi[4]=(short)f2bf(fa3.x); hi[5]=(short)f2bf(fa3.y); hi[6]=(short)f2bf(fa3.z); hi[7]=(short)f2bf(fa3.w);
        *(bf16x8*)&buf[row * 64 + ks0 * 8]       = lo;
        *(bf16x8*)&buf[row * 64 + (ks0 ^ 1) * 8] = hi;
    };
    auto writeA = [&](int tile, int h) {
        asm volatile("s_waitcnt vmcnt(2)" ::: "memory");   // fa loads done; trailing B stays in flight
        writeAcore(tile, h);
        asm volatile("s_waitcnt lgkmcnt(0)" ::: "memory"); // LDS write visible before barrier
    };

    // ---- fragment read / mfma helpers (all indices compile-time after inlining) ----
    auto readAF = [&](bf16x8 (&dst)[4][2], int tile, int MQ) {
        const ushort* pA = sA[tile & 1];
        #pragma unroll
        for (int m = 0; m < 4; m++)
            #pragma unroll
            for (int kh = 0; kh < 2; kh++)
                dst[m][kh] = *(const bf16x8*)&pA[(wr*128 + MQ*64 + m*16 + lr)*64 + (((kh*4+kb) ^ (lr&7)))*8];
    };
    auto readBV = [&](bf16x8 (&dst)[2][2], int tile, int NQ) {
        const ushort* pB = sB[tile & 1];
        #pragma unroll
        for (int n = 0; n < 2; n++)
            #pragma unroll
            for (int kh = 0; kh < 2; kh++)
                dst[n][kh] = *(const bf16x8*)&pB[(wc*64 + NQ*32 + n*16 + lr)*64 + (((kh*4+kb) ^ (lr&7)))*8];
    };
    auto mfma16 = [&](bf16x8 (&AF)[4][2], bf16x8 (&BV)[2][2], int MQ, int NQ) {
        #pragma unroll
        for (int m = 0; m < 4; m++)
            #pragma unroll
            for (int n = 0; n < 2; n++) {
                acc[MQ*4+m][NQ*2+n] = __builtin_amdgcn_mfma_f32_16x16x32_bf16(AF[m][0], BV[n][0], acc[MQ*4+m][NQ*2+n], 0, 0, 0);
                acc[MQ*4+m][NQ*2+n] = __builtin_amdgcn_mfma_f32_16x16x32_bf16(AF[m][1], BV[n][1], acc[MQ*4+m][NQ*2+n], 0, 0, 0);
            }
    };

    // ---- prologue: fully stage tiles 0 and 1, then pre-read p0's fragments ----
    if (A_F32) {
        #pragma unroll
        for (int x = 0; x < 2; x++)
            #pragma unroll
            for (int h = 0; h < 2; h++) {
                issueA(x, h);
                asm volatile("s_waitcnt vmcnt(0)" ::: "memory");
                writeAcore(x, h);
            }
    } else {
        #pragma unroll
        for (int x = 0; x < 2; x++) { stageAbf(x, 0); stageAbf(x, 1); }
    }
    #pragma unroll
    for (int x = 0; x < 2; x++) { stageB(x, 0); stageB(x, 1); }
    asm volatile("s_waitcnt vmcnt(0)" ::: "memory");
    __syncthreads();
    readAF(afX, 0, 0);
    readBV(bvX, 0, 0);

// phase: [reads for NEXT phase] | stage | vmcnt(6) | barrier | 16 MFMA (this phase's regs) | barrier
#define PHASE(AF, BV, MQ, NQ, READS, STAGES) { \
    READS \
    STAGES \
    asm volatile("s_waitcnt vmcnt(6)" ::: "memory"); \
    __builtin_amdgcn_s_barrier(); \
    asm volatile("" ::: "memory"); \
    __builtin_amdgcn_s_setprio(1); \
    mfma16(AF, BV, MQ, NQ); \
    __builtin_amdgcn_s_setprio(0); \
    asm volatile("" ::: "memory"); \
    __builtin_amdgcn_s_barrier(); \
    asm volatile("" ::: "memory"); \
}

    // ---- main loop: 8 iterations, 2 K-tiles each ----
    for (int i = 0; i < 8; i++) {
        const int t0 = 2 * i;
        // p0: (T0, M0, N0) with afX,bvX; read afY <- (T0, M1)
        PHASE(afX, bvX, 0, 0,
            { readAF(afY, t0, 1); },
            { if (i > 0) {
                  if (A_F32) { writeA(t0 + 1, 0); issueA(t0 + 1, 1); }
                  else stageAbf(t0 + 1, 1);
              } })
        // p1: (T0, M1, N0); read bvY <- (T0, N1)
        PHASE(afY, bvX, 1, 0,
            { readBV(bvY, t0, 1); },
            { if (i > 0) stageB(t0 + 1, 1); })
        // p2: (T0, M0, N1); no reads
        PHASE(afX, bvY, 0, 1,
            { },
            { if (A_F32 && i > 0) writeA(t0 + 1, 1);
              if (i < 7) { if (A_F32) issueA(t0 + 2, 0); else stageAbf(t0 + 2, 0); } })
        // p3: (T0, M1, N1); read afX,bvX <- (T1, M0/N0)
        PHASE(afY, bvY, 1, 1,
            { readAF(afX, t0 + 1, 0); readBV(bvX, t0 + 1, 0); },
            { if (i < 7) stageB(t0 + 2, 0);
              if (i == 7) asm volatile("s_waitcnt vmcnt(0)" ::: "memory"); })
        // p4: (T1, M0, N0); read afY <- (T1, M1)
        PHASE(afX, bvX, 0, 0,
            { readAF(afY, t0 + 1, 1); },
            { if (i < 7) {
                  if (A_F32) { writeA(t0 + 2, 0); issueA(t0 + 2, 1); }
                  else stageAbf(t0 + 2, 1);
              } })
        // p5: (T1, M1, N0); read bvY <- (T1, N1)
        PHASE(afY, bvX, 1, 0,
            { readBV(bvY, t0 + 1, 1); },
            { if (i < 7) stageB(t0 + 2, 1); })
        // p6: (T1, M0, N1); no reads
        PHASE(afX, bvY, 0, 1,
            { },
            { if (i < 7) {
                  if (A_F32) { writeA(t0 + 2, 1); issueA(t0 + 3, 0); }
                  else stageAbf(t0 + 3, 0);
              } })
        // p7: (T1, M1, N1); read afX,bvX <- (T0', M0/N0)
        PHASE(afY, bvY, 1, 1,
            { if (i < 7) { readAF(afX, t0 + 2, 0); readBV(bvX, t0 + 2, 0); } },
            { if (i < 7) stageB(t0 + 3, 0); })
    }
#undef PHASE

    // ---- epilogue ----
    float*  Cf = (float*)Cv;
    ushort* Cb = (ushort*)Cv;
    #pragma unroll
    for (int fm = 0; fm < 8; fm++) {
        #pragma unroll
        for (int fn = 0; fn < 4; fn++) {
            #pragma unroll
            for (int r = 0; r < 4; r++) {
                int row = m0 + wr * 128 + fm * 16 + (lane >> 4) * 4 + r;
                int col = n0 + wc * 64 + fn * 16 + lr;
                float v = acc[fm][fn][r];
                if (EPI == 1) v = 1.0f / (1.0f + __expf(-v));
                else if (EPI == 2) v = __expf(v);
                size_t idx = (size_t)row * N + col;
                if (OUT_BF) Cb[idx] = f2bf(v);
                else        Cf[idx] = v;
            }
        }
    }
}

// ---------------- scan pass A: per-chunk sums (bf16 in) ----------------
__global__ __launch_bounds__(256)
void scan_partials(const ushort* __restrict__ ke, const ushort* __restrict__ ev,
                   float* __restrict__ pke, float* __restrict__ pkv) {
    const int H = 1024, S = 8192, CHUNK = 32, BH = 4096;
    int h0 = threadIdx.x * 4;
    int c = blockIdx.x;
    int b = blockIdx.y;
    size_t base = ((size_t)b * S + (size_t)c * CHUNK) * H + h0;
    float se0 = 0.f, se1 = 0.f, se2 = 0.f, se3 = 0.f;
    float sv0 = 0.f, sv1 = 0.f, sv2 = 0.f, sv3 = 0.f;
    for (int s = 0; s < CHUNK; s++) {
        ushort4 e4 = *(const ushort4*)(ke + base + (size_t)s * H);
        ushort4 v4 = *(const ushort4*)(ev + base + (size_t)s * H);
        float e0 = bf2f(e4.x), e1 = bf2f(e4.y), e2 = bf2f(e4.z), e3 = bf2f(e4.w);
        se0 += e0; se1 += e1; se2 += e2; se3 += e3;
        sv0 += e0 * bf2f(v4.x); sv1 += e1 * bf2f(v4.y);
        sv2 += e2 * bf2f(v4.z); sv3 += e3 * bf2f(v4.w);
    }
    size_t p = (size_t)c * BH + b * H + h0;
    *(float4*)(pke + p) = make_float4(se0, se1, se2, se3);
    *(float4*)(pkv + p) = make_float4(sv0, sv1, sv2, sv3);
}

// ---------------- scan pass B: exclusive prefix over chunks ----------------
__global__ __launch_bounds__(256)
void scan_offsets(float* __restrict__ pke, float* __restrict__ pkv, int nch, int BH) {
    int i = blockIdx.x * blockDim.x + threadIdx.x;
    if (i >= BH) return;
    float rke = 0.f, rkv = 0.f;
    for (int c = 0; c < nch; c++) {
        size_t idx = (size_t)c * BH + i;
        float a = pke[idx], b = pkv[idx];
        pke[idx] = rke; pkv[idx] = rkv;
        rke += a; rkv += b;
    }
}

// ---------------- scan pass C: inclusive scan + y = sigmoid(emb_q)*(kv/ke) ----------------
__global__ __launch_bounds__(256)
void scan_final(const ushort* __restrict__ ke, const ushort* __restrict__ ev,
                const ushort* __restrict__ sq,
                const float* __restrict__ pke, const float* __restrict__ pkv,
                ushort* __restrict__ ybf) {
    const int H = 1024, S = 8192, CHUNK = 32, BH = 4096;
    int h0 = threadIdx.x * 4;
    int c = blockIdx.x;
    int b = blockIdx.y;
    size_t p = (size_t)c * BH + b * H + h0;
    float4 rke = *(const float4*)(pke + p);
    float4 rkv = *(const float4*)(pkv + p);
    size_t base = ((size_t)b * S + (size_t)c * CHUNK) * H + h0;
    for (int s = 0; s < CHUNK; s++) {
        size_t idx = base + (size_t)s * H;
        ushort4 e4 = *(const ushort4*)(ke + idx);
        ushort4 v4 = *(const ushort4*)(ev + idx);
        ushort4 q4 = *(const ushort4*)(sq + idx);
        float e0 = bf2f(e4.x), e1 = bf2f(e4.y), e2 = bf2f(e4.z), e3 = bf2f(e4.w);
        rke.x += e0; rke.y += e1; rke.z += e2; rke.w += e3;
        rkv.x += e0 * bf2f(v4.x); rkv.y += e1 * bf2f(v4.y);
        rkv.z += e2 * bf2f(v4.z); rkv.w += e3 * bf2f(v4.w);
        ushort4 o;
        o.x = f2bf(bf2f(q4.x) * (rkv.x / rke.x));
        o.y = f2bf(bf2f(q4.y) * (rkv.y / rke.y));
        o.z = f2bf(bf2f(q4.z) * (rkv.z / rke.z));
        o.w = f2bf(bf2f(q4.w) * (rkv.w / rke.w));
        *(ushort4*)(ybf + idx) = o;
    }
}

extern "C" void kernel_launch(void* const* d_in, const int* in_sizes, int n_in,
                              void* d_out, int out_size, void* d_ws, size_t ws_size,
                              hipStream_t stream) {
    const float* q   = (const float*)d_in[0];
    const float* k   = (const float*)d_in[1];
    const float* v   = (const float*)d_in[2];
    const float* w_q = (const float*)d_in[3];
    const float* w_k = (const float*)d_in[4];
    const float* w_v = (const float*)d_in[5];
    const float* w_p = (const float*)d_in[6];
    float* out = (float*)d_out;

    const int B = 4, S = 8192, H = 1024;
    const int M = B * S;                  // 32768
    const size_t MH = (size_t)M * H;      // 33,554,432
    const int NCH = 256;                  // CHUNK = 32
    const int BH = B * H;                 // 4096

    char* ws = (char*)d_ws;
    size_t off = 0;
    auto alloc = [&](size_t bytes) -> char* {
        char* p = ws + off;
        off += (bytes + 255) & ~(size_t)255;
        return p;
    };
    ushort* ybuf = (ushort*)alloc(MH * 2);
    ushort* wqt  = (ushort*)alloc((size_t)H * H * 2);
    ushort* wkt  = (ushort*)alloc((size_t)H * H * 2);
    ushort* wvt  = (ushort*)alloc((size_t)H * H * 2);
    ushort* wpt  = (ushort*)alloc((size_t)H * H * 2);
    ushort* sqb  = (ushort*)alloc(MH * 2);
    ushort* keb  = (ushort*)alloc(MH * 2);
    ushort* evb  = (ushort*)alloc(MH * 2);
    float*  pke  = (float*)alloc((size_t)NCH * BH * 4);
    float*  pkv  = (float*)alloc((size_t)NCH * BH * 4);

    dim3 tg(H / 32, H / 32);
    const int ngg = (M / 256) * (H / 256);   // 512 blocks
    dim3 gs(NCH, B);

    transpose_to_bf16<<<tg, 256, 0, stream>>>(w_q, wqt, H, H);
    transpose_to_bf16<<<tg, 256, 0, stream>>>(w_k, wkt, H, H);
    transpose_to_bf16<<<tg, 256, 0, stream>>>(w_v, wvt, H, H);
    transpose_to_bf16<<<tg, 256, 0, stream>>>(w_p, wpt, H, H);

    // projections: fused fp32->bf16 A staging + epilogue, bf16 outputs
    gemm256<1, 1, 1><<<ngg, 512, 0, stream>>>(q, wqt, sqb);
    gemm256<2, 1, 1><<<ngg, 512, 0, stream>>>(k, wkt, keb);
    gemm256<0, 1, 1><<<ngg, 512, 0, stream>>>(v, wvt, evb);

    // hierarchical scan over S
    scan_partials<<<gs, 256, 0, stream>>>(keb, evb, pke, pkv);
    scan_offsets<<<BH / 256, 256, 0, stream>>>(pke, pkv, NCH, BH);
    scan_final<<<gs, 256, 0, stream>>>(keb, evb, sqb, pke, pkv, ybuf);

    // out = y @ w_p (bf16 A via global_load_lds, fp32 out)
    gemm256<0, 0, 0><<<ngg, 512, 0, stream>>>(ybuf, wpt, out);
}

// Round 5
// 616.939 us; speedup vs baseline: 1.5701x; 1.5701x over previous
//
#include <hip/hip_runtime.h>
#include <hip/hip_bf16.h>
#include <cstdint>

#define AS_GLOBAL __attribute__((address_space(1)))
#define AS_LDS    __attribute__((address_space(3)))

typedef __attribute__((ext_vector_type(8))) short bf16x8;
typedef __attribute__((ext_vector_type(4))) float f32x4;

static __device__ __forceinline__ ushort f2bf(float x) {
    union { float f; uint32_t u; } c;
    c.f = x;
    uint32_t u = c.u;
    u += 0x7fffu + ((u >> 16) & 1u);   // RTNE
    return (ushort)(u >> 16);
}
static __device__ __forceinline__ float bf2f(ushort u) {
    union { uint32_t i; float f; } c;
    c.i = ((uint32_t)u) << 16;
    return c.f;
}

// async global->LDS, 16B/lane. LDS dest = wave-uniform base + lane*16 (we pass base+lane*16).
static __device__ __forceinline__ void gload_lds16(const void* g, void* l) {
    __builtin_amdgcn_global_load_lds(
        (const AS_GLOBAL uint32_t*)(uintptr_t)g,
        (AS_LDS uint32_t*)(uint32_t)(uintptr_t)l,
        16, 0, 0);
}

// ---------------- [K,N] fp32 -> [N,K] bf16 transpose ----------------
__global__ __launch_bounds__(256)
void transpose_to_bf16(const float* __restrict__ w, ushort* __restrict__ wt, int K, int N) {
    __shared__ float tile[32][33];
    int bn = blockIdx.x * 32;
    int bk = blockIdx.y * 32;
    int tx = threadIdx.x & 31, ty = threadIdx.x >> 5;
    #pragma unroll
    for (int i = 0; i < 32; i += 8)
        tile[ty + i][tx] = w[(size_t)(bk + ty + i) * N + bn + tx];
    __syncthreads();
    #pragma unroll
    for (int i = 0; i < 32; i += 8)
        wt[(size_t)(bn + ty + i) * K + bk + tx] = f2bf(tile[tx][ty + i]);
}

// =====================================================================
// 256x256 8-phase GEMM, template-form in-phase fragment reads.
// C[M,1024] = A[M,1024] * Bt[1024,1024](bf16). M=32768. BK=64, 16 K-tiles.
// EPI: 0=none 1=sigmoid 2=exp.  A_F32: fused fp32->bf16 A staging.  OUT_BF: bf16 C.
// =====================================================================
template<int EPI, int A_F32, int OUT_BF>
__global__ __launch_bounds__(512, 2)
void gemm256(const void* __restrict__ Av, const ushort* __restrict__ Bt,
             void* __restrict__ Cv) {
    constexpr int K = 1024, N = 1024;
    __shared__ ushort sA[2][16384];   // [buf][row*64 + physslot*8], 32KB each
    __shared__ ushort sB[2][16384];
    const int tid  = threadIdx.x;
    const int wid  = tid >> 6;
    const int lane = tid & 63;
    const int wr = wid >> 2, wc = wid & 3;        // 2 x 4 waves, each owns 128x64 of C
    const int lr = lane & 15, kb = lane >> 4;

    // XCD swizzle: 512 wgs = 8 xcds x 64; same-xcd blocks share a bm range (A reuse in L2)
    const int wg = blockIdx.x;
    const int xcd = wg & 7, local = wg >> 3;
    const int bm = xcd * 16 + (local >> 2);
    const int bn = local & 3;
    const int m0 = bm * 256, n0 = bn * 256;

    const float*  Af = (const float*)Av;
    const ushort* Ab = (const ushort*)Av;

    f32x4 acc[8][4] = {};
    bf16x8 af[4][2];                  // single A fragment set, overwritten per phase
    bf16x8 bvX[2][2], bvY[2][2];      // B fragment sets for NQ=0 / NQ=1
    float4 fa0, fa1, fa2, fa3;        // in-flight fp32 A (reg stage)
    const int arl  = tid >> 2;
    const int aseg = tid & 3;
    const int agr0 = ((arl >> 6) << 7) + (arl & 63);

    // ---- staging helpers (LDS linear dest, pre-swizzled global source) ----
    // stageA h: rows {0-63,128-191} for h=0 (MQ=0 rows), {64-127,192-255} for h=1 (MQ=1)
    // stageB h: rows = NQ=h fragment rows for all wc
    auto stageB = [&](int tile, int h) {
        ushort* buf = sB[tile & 1];
        const int kt0 = tile * 64;
        #pragma unroll
        for (int j = 0; j < 2; j++) {
            const int row0 = j * 128 + h * 32 + (wid >> 2) * 64 + (wid & 3) * 8;
            const int row  = row0 + (lane >> 3);
            const int kslot = (lane & 7) ^ (lane >> 3);
            gload_lds16(Bt + (size_t)(n0 + row) * K + kt0 + kslot * 8,
                        &buf[row * 64 + (lane & 7) * 8]);
        }
    };
    auto stageAbf = [&](int tile, int h) {
        ushort* buf = sA[tile & 1];
        const int kt0 = tile * 64;
        #pragma unroll
        for (int j = 0; j < 2; j++) {
            const int row0 = j * 128 + h * 64 + wid * 8;
            const int row  = row0 + (lane >> 3);
            const int kslot = (lane & 7) ^ (lane >> 3);
            gload_lds16(Ab + (size_t)(m0 + row) * K + kt0 + kslot * 8,
                        &buf[row * 64 + (lane & 7) * 8]);
        }
    };
    auto issueA = [&](int tile, int h) {
        const int row = agr0 + h * 64;
        const float* s = Af + (size_t)(m0 + row) * K + tile * 64 + aseg * 16;
        fa0 = *(const float4*)(s);     fa1 = *(const float4*)(s + 4);
        fa2 = *(const float4*)(s + 8); fa3 = *(const float4*)(s + 12);
    };
    auto writeAcore = [&](int tile, int h) {
        const int row = agr0 + h * 64;
        const int ks0 = (aseg * 2) ^ (row & 7);
        ushort* buf = sA[tile & 1];
        bf16x8 lo, hi;
        lo[0]=(short)f2bf(fa0.x); lo[1]=(short)f2bf(fa0.y); lo[2]=(short)f2bf(fa0.z); lo[3]=(short)f2bf(fa0.w);
        lo[4]=(short)f2bf(fa1.x); lo[5]=(short)f2bf(fa1.y); lo[6]=(short)f2bf(fa1.z); lo[7]=(short)f2bf(fa1.w);
        hi[0]=(short)f2bf(fa2.x); hi[1]=(short)f2bf(fa2.y); hi[2]=(short)f2bf(fa2.z); hi[3]=(short)f2bf(fa2.w);
        hi[4]=(short)f2bf(fa3.x); hi[5]=(short)f2bf(fa3.y); hi[6]=(short)f2bf(fa3.z); hi[7]=(short)f2bf(fa3.w);
        *(bf16x8*)&buf[row * 64 + ks0 * 8]       = lo;
        *(bf16x8*)&buf[row * 64 + (ks0 ^ 1) * 8] = hi;
    };
    auto writeA = [&](int tile, int h) {
        asm volatile("s_waitcnt vmcnt(2)" ::: "memory");   // fa loads done; trailing B gloads stay in flight
        writeAcore(tile, h);
        asm volatile("s_waitcnt lgkmcnt(0)" ::: "memory"); // ds_write visible before next barrier
    };

    // ---- fragment reads (in-phase) ----
    auto readAF = [&](int tile, int MQ) {
        const ushort* pA = sA[tile & 1];
        #pragma unroll
        for (int m = 0; m < 4; m++)
            #pragma unroll
            for (int kh = 0; kh < 2; kh++)
                af[m][kh] = *(const bf16x8*)&pA[(wr*128 + MQ*64 + m*16 + lr)*64 + (((kh*4+kb) ^ (lr&7)))*8];
    };
    auto readBV = [&](bf16x8 (&dst)[2][2], int tile, int NQ) {
        const ushort* pB = sB[tile & 1];
        #pragma unroll
        for (int n = 0; n < 2; n++)
            #pragma unroll
            for (int kh = 0; kh < 2; kh++)
                dst[n][kh] = *(const bf16x8*)&pB[(wc*64 + NQ*32 + n*16 + lr)*64 + (((kh*4+kb) ^ (lr&7)))*8];
    };
    auto mfma16 = [&](bf16x8 (&BV)[2][2], int MQ, int NQ) {
        #pragma unroll
        for (int m = 0; m < 4; m++)
            #pragma unroll
            for (int n = 0; n < 2; n++) {
                acc[MQ*4+m][NQ*2+n] = __builtin_amdgcn_mfma_f32_16x16x32_bf16(af[m][0], BV[n][0], acc[MQ*4+m][NQ*2+n], 0, 0, 0);
                acc[MQ*4+m][NQ*2+n] = __builtin_amdgcn_mfma_f32_16x16x32_bf16(af[m][1], BV[n][1], acc[MQ*4+m][NQ*2+n], 0, 0, 0);
            }
    };

    // ---- prologue: fully stage tiles 0 and 1 ----
    if (A_F32) {
        #pragma unroll
        for (int x = 0; x < 2; x++)
            #pragma unroll
            for (int h = 0; h < 2; h++) {
                issueA(x, h);
                asm volatile("s_waitcnt vmcnt(0)" ::: "memory");
                writeAcore(x, h);
            }
    } else {
        #pragma unroll
        for (int x = 0; x < 2; x++) { stageAbf(x, 0); stageAbf(x, 1); }
    }
    #pragma unroll
    for (int x = 0; x < 2; x++) { stageB(x, 0); stageB(x, 1); }
    asm volatile("s_waitcnt vmcnt(0)" ::: "memory");
    __syncthreads();

// phase: [in-phase frag reads] [stage] barrier; lgkmcnt(0); sched_barrier; 16 MFMA; barrier
#define PHASE(BV, MQ, NQ, READS, STAGES) { \
    READS \
    STAGES \
    asm volatile("" ::: "memory"); \
    __builtin_amdgcn_s_barrier(); \
    asm volatile("s_waitcnt lgkmcnt(0)" ::: "memory"); \
    __builtin_amdgcn_sched_barrier(0); \
    __builtin_amdgcn_s_setprio(1); \
    mfma16(BV, MQ, NQ); \
    __builtin_amdgcn_s_setprio(0); \
    asm volatile("" ::: "memory"); \
    __builtin_amdgcn_s_barrier(); \
    asm volatile("" ::: "memory"); \
}

    // ---- main loop: 8 iterations, 2 K-tiles each ----
    // stage placement (derived WAR-safe): buf0 halves writable after their last
    // reader phase + 1 barrier; A h0 last read p0, A h1 p2, B h0 p0, B h1 p1 (per tile).
    for (int i = 0; i < 8; i++) {
        const int t0 = 2 * i;
        // p0: MFMA(T0,M0,N0); reads af(T0,M0)+bvX(T0,N0)
        PHASE(bvX, 0, 0,
            { readAF(t0, 0); readBV(bvX, t0, 0); },
            { if (!A_F32) asm volatile("s_waitcnt vmcnt(8)" ::: "memory"); })
        // p1: MFMA(T0,M0,N1); reads bvY(T0,N1)
        PHASE(bvY, 0, 1,
            { readBV(bvY, t0, 1); },
            { if (i < 7) {
                  if (A_F32) issueA(t0 + 2, 0); else stageAbf(t0 + 2, 0);
                  stageB(t0 + 2, 0);
              } })
        // p2: MFMA(T0,M1,N0); reads af(T0,M1)
        PHASE(bvX, 1, 0,
            { readAF(t0, 1); },
            { if (i < 7) {
                  if (A_F32) { writeA(t0 + 2, 0); issueA(t0 + 2, 1); }
                  stageB(t0 + 2, 1);
              } })
        // p3: MFMA(T0,M1,N1)
        PHASE(bvY, 1, 1,
            { },
            { if (i < 7) {
                  if (A_F32) writeA(t0 + 2, 1); else stageAbf(t0 + 2, 1);
              }
              if (i == 7) asm volatile("s_waitcnt vmcnt(0)" ::: "memory"); })
        // p4: MFMA(T1,M0,N0); reads af(T1,M0)+bvX(T1,N0)
        PHASE(bvX, 0, 0,
            { readAF(t0 + 1, 0); readBV(bvX, t0 + 1, 0); },
            { if (!A_F32) asm volatile("s_waitcnt vmcnt(8)" ::: "memory"); })
        // p5: MFMA(T1,M0,N1); reads bvY(T1,N1)
        PHASE(bvY, 0, 1,
            { readBV(bvY, t0 + 1, 1); },
            { if (i < 7) {
                  if (A_F32) issueA(t0 + 3, 0); else stageAbf(t0 + 3, 0);
                  stageB(t0 + 3, 0);
              } })
        // p6: MFMA(T1,M1,N0); reads af(T1,M1)
        PHASE(bvX, 1, 0,
            { readAF(t0 + 1, 1); },
            { if (i < 7) {
                  if (A_F32) { writeA(t0 + 3, 0); issueA(t0 + 3, 1); }
                  stageB(t0 + 3, 1);
              } })
        // p7: MFMA(T1,M1,N1)
        PHASE(bvY, 1, 1,
            { },
            { if (i < 7) {
                  if (A_F32) writeA(t0 + 3, 1); else stageAbf(t0 + 3, 1);
              } })
    }
#undef PHASE

    // ---- epilogue ----
    float*  Cf = (float*)Cv;
    ushort* Cb = (ushort*)Cv;
    #pragma unroll
    for (int fm = 0; fm < 8; fm++) {
        #pragma unroll
        for (int fn = 0; fn < 4; fn++) {
            #pragma unroll
            for (int r = 0; r < 4; r++) {
                int row = m0 + wr * 128 + fm * 16 + (lane >> 4) * 4 + r;
                int col = n0 + wc * 64 + fn * 16 + lr;
                float v = acc[fm][fn][r];
                if (EPI == 1) v = 1.0f / (1.0f + __expf(-v));
                else if (EPI == 2) v = __expf(v);
                size_t idx = (size_t)row * N + col;
                if (OUT_BF) Cb[idx] = f2bf(v);
                else        Cf[idx] = v;
            }
        }
    }
}

// ---------------- scan pass A: per-chunk sums (bf16 in) ----------------
__global__ __launch_bounds__(256)
void scan_partials(const ushort* __restrict__ ke, const ushort* __restrict__ ev,
                   float* __restrict__ pke, float* __restrict__ pkv) {
    const int H = 1024, S = 8192, CHUNK = 32, BH = 4096;
    int h0 = threadIdx.x * 4;
    int c = blockIdx.x;
    int b = blockIdx.y;
    size_t base = ((size_t)b * S + (size_t)c * CHUNK) * H + h0;
    float se0 = 0.f, se1 = 0.f, se2 = 0.f, se3 = 0.f;
    float sv0 = 0.f, sv1 = 0.f, sv2 = 0.f, sv3 = 0.f;
    for (int s = 0; s < CHUNK; s++) {
        ushort4 e4 = *(const ushort4*)(ke + base + (size_t)s * H);
        ushort4 v4 = *(const ushort4*)(ev + base + (size_t)s * H);
        float e0 = bf2f(e4.x), e1 = bf2f(e4.y), e2 = bf2f(e4.z), e3 = bf2f(e4.w);
        se0 += e0; se1 += e1; se2 += e2; se3 += e3;
        sv0 += e0 * bf2f(v4.x); sv1 += e1 * bf2f(v4.y);
        sv2 += e2 * bf2f(v4.z); sv3 += e3 * bf2f(v4.w);
    }
    size_t p = (size_t)c * BH + b * H + h0;
    *(float4*)(pke + p) = make_float4(se0, se1, se2, se3);
    *(float4*)(pkv + p) = make_float4(sv0, sv1, sv2, sv3);
}

// ---------------- scan pass B: exclusive prefix over chunks ----------------
__global__ __launch_bounds__(256)
void scan_offsets(float* __restrict__ pke, float* __restrict__ pkv, int nch, int BH) {
    int i = blockIdx.x * blockDim.x + threadIdx.x;
    if (i >= BH) return;
    float rke = 0.f, rkv = 0.f;
    for (int c = 0; c < nch; c++) {
        size_t idx = (size_t)c * BH + i;
        float a = pke[idx], b = pkv[idx];
        pke[idx] = rke; pkv[idx] = rkv;
        rke += a; rkv += b;
    }
}

// ---------------- scan pass C: inclusive scan + y = sigmoid(emb_q)*(kv/ke) ----------------
__global__ __launch_bounds__(256)
void scan_final(const ushort* __restrict__ ke, const ushort* __restrict__ ev,
                const ushort* __restrict__ sq,
                const float* __restrict__ pke, const float* __restrict__ pkv,
                ushort* __restrict__ ybf) {
    const int H = 1024, S = 8192, CHUNK = 32, BH = 4096;
    int h0 = threadIdx.x * 4;
    int c = blockIdx.x;
    int b = blockIdx.y;
    size_t p = (size_t)c * BH + b * H + h0;
    float4 rke = *(const float4*)(pke + p);
    float4 rkv = *(const float4*)(pkv + p);
    size_t base = ((size_t)b * S + (size_t)c * CHUNK) * H + h0;
    for (int s = 0; s < CHUNK; s++) {
        size_t idx = base + (size_t)s * H;
        ushort4 e4 = *(const ushort4*)(ke + idx);
        ushort4 v4 = *(const ushort4*)(ev + idx);
        ushort4 q4 = *(const ushort4*)(sq + idx);
        float e0 = bf2f(e4.x), e1 = bf2f(e4.y), e2 = bf2f(e4.z), e3 = bf2f(e4.w);
        rke.x += e0; rke.y += e1; rke.z += e2; rke.w += e3;
        rkv.x += e0 * bf2f(v4.x); rkv.y += e1 * bf2f(v4.y);
        rkv.z += e2 * bf2f(v4.z); rkv.w += e3 * bf2f(v4.w);
        ushort4 o;
        o.x = f2bf(bf2f(q4.x) * (rkv.x / rke.x));
        o.y = f2bf(bf2f(q4.y) * (rkv.y / rke.y));
        o.z = f2bf(bf2f(q4.z) * (rkv.z / rke.z));
        o.w = f2bf(bf2f(q4.w) * (rkv.w / rke.w));
        *(ushort4*)(ybf + idx) = o;
    }
}

extern "C" void kernel_launch(void* const* d_in, const int* in_sizes, int n_in,
                              void* d_out, int out_size, void* d_ws, size_t ws_size,
                              hipStream_t stream) {
    const float* q   = (const float*)d_in[0];
    const float* k   = (const float*)d_in[1];
    const float* v   = (const float*)d_in[2];
    const float* w_q = (const float*)d_in[3];
    const float* w_k = (const float*)d_in[4];
    const float* w_v = (const float*)d_in[5];
    const float* w_p = (const float*)d_in[6];
    float* out = (float*)d_out;

    const int B = 4, S = 8192, H = 1024;
    const int M = B * S;                  // 32768
    const size_t MH = (size_t)M * H;      // 33,554,432
    const int NCH = 256;                  // CHUNK = 32
    const int BH = B * H;                 // 4096

    char* ws = (char*)d_ws;
    size_t off = 0;
    auto alloc = [&](size_t bytes) -> char* {
        char* p = ws + off;
        off += (bytes + 255) & ~(size_t)255;
        return p;
    };
    ushort* ybuf = (ushort*)alloc(MH * 2);
    ushort* wqt  = (ushort*)alloc((size_t)H * H * 2);
    ushort* wkt  = (ushort*)alloc((size_t)H * H * 2);
    ushort* wvt  = (ushort*)alloc((size_t)H * H * 2);
    ushort* wpt  = (ushort*)alloc((size_t)H * H * 2);
    ushort* sqb  = (ushort*)alloc(MH * 2);
    ushort* keb  = (ushort*)alloc(MH * 2);
    ushort* evb  = (ushort*)alloc(MH * 2);
    float*  pke  = (float*)alloc((size_t)NCH * BH * 4);
    float*  pkv  = (float*)alloc((size_t)NCH * BH * 4);

    dim3 tg(H / 32, H / 32);
    const int ngg = (M / 256) * (H / 256);   // 512 blocks
    dim3 gs(NCH, B);

    transpose_to_bf16<<<tg, 256, 0, stream>>>(w_q, wqt, H, H);
    transpose_to_bf16<<<tg, 256, 0, stream>>>(w_k, wkt, H, H);
    transpose_to_bf16<<<tg, 256, 0, stream>>>(w_v, wvt, H, H);
    transpose_to_bf16<<<tg, 256, 0, stream>>>(w_p, wpt, H, H);

    // projections: fused fp32->bf16 A staging + epilogue, bf16 outputs
    gemm256<1, 1, 1><<<ngg, 512, 0, stream>>>(q, wqt, sqb);
    gemm256<2, 1, 1><<<ngg, 512, 0, stream>>>(k, wkt, keb);
    gemm256<0, 1, 1><<<ngg, 512, 0, stream>>>(v, wvt, evb);

    // hierarchical scan over S
    scan_partials<<<gs, 256, 0, stream>>>(keb, evb, pke, pkv);
    scan_offsets<<<BH / 256, 256, 0, stream>>>(pke, pkv, NCH, BH);
    scan_final<<<gs, 256, 0, stream>>>(keb, evb, sqb, pke, pkv, ybuf);

    // out = y @ w_p (bf16 A via global_load_lds, fp32 out)
    gemm256<0, 0, 0><<<ngg, 512, 0, stream>>>(ybuf, wpt, out);
}